// Round 1
// baseline (380.196 us; speedup 1.0000x reference)
//
#include <hip/hip_runtime.h>

// SparseWeights: y = x @ (W_dense + scatter(sparse))^T + bias
// x: [T=8192, K=4096] f32, W: [M=4096, K=4096] f32, out: [T, M] f32.
// Strategy: cast x,W to bf16 (threshold 0.154 >> bf16 GEMM error ~0.01),
// then m97-structure 128x128 bf16 MFMA GEMM (B^T layout, global_load_lds).

typedef __attribute__((ext_vector_type(8))) __bf16 bf16x8;
typedef __attribute__((ext_vector_type(4))) float f32x4;
typedef __attribute__((ext_vector_type(8))) unsigned short u16x8;

__device__ __forceinline__ unsigned short f2bf(float f) {
  unsigned int u = __builtin_bit_cast(unsigned int, f);
  u += 0x7FFFu + ((u >> 16) & 1u);   // round-to-nearest-even
  return (unsigned short)(u >> 16);
}

// ---- prepass 1/3: f32 -> bf16 bulk convert (vectorized x8) ----
__global__ __launch_bounds__(256) void cvt_f32_bf16(
    const float* __restrict__ s, unsigned short* __restrict__ d, long n8) {
  long i = (long)blockIdx.x * blockDim.x + threadIdx.x;
  const long stride = (long)gridDim.x * blockDim.x;
  for (; i < n8; i += stride) {
    const float4* sp = (const float4*)(s + i * 8);
    float4 a = sp[0];
    float4 b = sp[1];
    u16x8 o;
    o[0] = f2bf(a.x); o[1] = f2bf(a.y); o[2] = f2bf(a.z); o[3] = f2bf(a.w);
    o[4] = f2bf(b.x); o[5] = f2bf(b.y); o[6] = f2bf(b.z); o[7] = f2bf(b.w);
    *(u16x8*)(d + i * 8) = o;
  }
}

// ---- prepass 2/3: scatter sparse values into bf16 W ----
// (row,col) pairs are unique -> no atomics; runs after cvt (stream-ordered).
__global__ __launch_bounds__(256) void sparse_scatter(
    const float* __restrict__ dense, const float* __restrict__ vals,
    const int* __restrict__ rows, const int* __restrict__ cols,
    unsigned short* __restrict__ Wb, int nnz, int K) {
  int i = blockIdx.x * blockDim.x + threadIdx.x;
  if (i < nnz) {
    size_t off = (size_t)rows[i] * (size_t)K + (size_t)cols[i];
    Wb[off] = f2bf(dense[off] + vals[i]);
  }
}

// ---- GEMM: C[T,M] = A[T,K](bf16) * B[M,K](bf16)^T + bias ----
// m97 structure: 128x128 tile, BK=32, 256 threads (4 waves, 2x2),
// each wave 64x64 = 4x4 frags of mfma_f32_16x16x32_bf16.
constexpr int BM = 128, BN = 128, BK = 32;

__global__ __launch_bounds__(256, 2) void gemm_bt_bf16(
    const unsigned short* __restrict__ A,   // [Tm][K] bf16
    const unsigned short* __restrict__ B,   // [Mn][K] bf16
    const float* __restrict__ bias,         // [Mn]
    float* __restrict__ C,                  // [Tm][Mn] f32
    int Tm, int Mn, int K) {
  __shared__ unsigned short As[BM * BK];   // 8 KiB, linear [128][32]
  __shared__ unsigned short Bs[BN * BK];   // 8 KiB

  const int tid = threadIdx.x;
  const int lane = tid & 63;
  const int wave = tid >> 6;

  // XCD-aware bijective swizzle (nwg = 2048, % 8 == 0)
  const int nwg = gridDim.x;
  const int cpx = nwg >> 3;
  int bid = blockIdx.x;
  bid = (bid & 7) * cpx + (bid >> 3);

  const int ntn = Mn / BN;                 // 32 col-tiles
  const int bm0 = (bid / ntn) * BM;
  const int bn0 = (bid % ntn) * BN;

  // Staging: thread t fills LDS bytes [t*16) (round 0) and [4096 + t*16) (round 1).
  // Linear LDS byte o -> row o/64, elem col (o%64)/2.
  const int srow = tid >> 2;               // 0..63
  const int scol = (tid & 3) * 8;          // 0,8,16,24
  const unsigned short* Ag = A + (size_t)(bm0 + srow) * K + scol;
  const unsigned short* Bg = B + (size_t)(bn0 + srow) * K + scol;
  unsigned short* Al = As + tid * 8;       // +16 B per thread (wave-linear)
  unsigned short* Bl = Bs + tid * 8;
  const size_t half = (size_t)64 * K;      // +64 rows for round 1

  // Wave's 64x64 output corner; fragment lane decomposition.
  const int wm = (wave >> 1) * 64;
  const int wn = (wave & 1) * 64;
  const int fr = lane & 15;                // row/col within 16x16 frag
  const int fk = (lane >> 4) * 8;          // k-chunk (8 consecutive bf16)

  f32x4 acc[4][4] = {};

  for (int k0 = 0; k0 < K; k0 += BK) {
    __builtin_amdgcn_global_load_lds(
        (const __attribute__((address_space(1))) void*)(Ag + k0),
        (__attribute__((address_space(3))) void*)(Al), 16, 0, 0);
    __builtin_amdgcn_global_load_lds(
        (const __attribute__((address_space(1))) void*)(Ag + half + k0),
        (__attribute__((address_space(3))) void*)(Al + 2048), 16, 0, 0);
    __builtin_amdgcn_global_load_lds(
        (const __attribute__((address_space(1))) void*)(Bg + k0),
        (__attribute__((address_space(3))) void*)(Bl), 16, 0, 0);
    __builtin_amdgcn_global_load_lds(
        (const __attribute__((address_space(1))) void*)(Bg + half + k0),
        (__attribute__((address_space(3))) void*)(Bl + 2048), 16, 0, 0);
    __syncthreads();   // drains vmcnt(0) -> staged data visible

    bf16x8 a[4], b[4];
#pragma unroll
    for (int i = 0; i < 4; ++i)
      a[i] = *reinterpret_cast<const bf16x8*>(&As[(wm + i * 16 + fr) * BK + fk]);
#pragma unroll
    for (int j = 0; j < 4; ++j)
      b[j] = *reinterpret_cast<const bf16x8*>(&Bs[(wn + j * 16 + fr) * BK + fk]);

#pragma unroll
    for (int i = 0; i < 4; ++i)
#pragma unroll
      for (int j = 0; j < 4; ++j)
        acc[i][j] = __builtin_amdgcn_mfma_f32_16x16x32_bf16(a[i], b[j], acc[i][j], 0, 0, 0);

    __syncthreads();   // protect LDS from next iteration's staging
  }

  // Epilogue: C/D layout col = lane&15, row = (lane>>4)*4 + reg.
  const int c4 = (lane >> 4) * 4;
  const int cc = lane & 15;
#pragma unroll
  for (int j = 0; j < 4; ++j) {
    const int col = bn0 + wn + j * 16 + cc;
    const float bv = bias[col];
#pragma unroll
    for (int i = 0; i < 4; ++i) {
      const int row = bm0 + wm + i * 16 + c4;
#pragma unroll
      for (int q = 0; q < 4; ++q)
        C[(size_t)(row + q) * Mn + col] = acc[i][j][q] + bv;
    }
  }
}

extern "C" void kernel_launch(void* const* d_in, const int* in_sizes, int n_in,
                              void* d_out, int out_size, void* d_ws, size_t ws_size,
                              hipStream_t stream) {
  const float* x     = (const float*)d_in[0];   // [T, K]
  const float* dw    = (const float*)d_in[1];   // [M, K]
  const float* bias  = (const float*)d_in[2];   // [M]
  const float* sv    = (const float*)d_in[3];   // [nnz]
  const int*   rows  = (const int*)d_in[4];
  const int*   cols  = (const int*)d_in[5];
  float* out = (float*)d_out;

  const int  Mn = in_sizes[2];                       // 4096
  const long wElems = (long)in_sizes[1];             // M*K
  const int  K  = (int)(wElems / Mn);                // 4096
  const long xElems = (long)in_sizes[0];             // T*K
  const int  Tm = (int)(xElems / K);                 // 8192
  const int  nnz = in_sizes[3];

  // Workspace layout: Wb bf16 [M*K] (33.5 MB), Xb bf16 [T*K] (67 MB).
  unsigned short* Wb = (unsigned short*)d_ws;
  unsigned short* Xb = Wb + wElems;

  cvt_f32_bf16<<<2048, 256, 0, stream>>>(dw, Wb, wElems / 8);
  sparse_scatter<<<(nnz + 255) / 256, 256, 0, stream>>>(dw, sv, rows, cols, Wb, nnz, K);
  cvt_f32_bf16<<<2048, 256, 0, stream>>>(x, Xb, xElems / 8);

  dim3 grid((Tm / BM) * (Mn / BN));   // 64*32 = 2048
  gemm_bt_bf16<<<grid, 256, 0, stream>>>(Xb, Wb, bias, out, Tm, Mn, K);
}

// Round 2
// 322.205 us; speedup vs baseline: 1.1800x; 1.1800x over previous
//
#include <hip/hip_runtime.h>

// SparseWeights: y = x @ (W_dense + scatter(sparse))^T + bias
// Round 2: 256x256-tile, BK=32, 4-deep-ring, 2-phase/K-tile deep-pipelined
// bf16 MFMA GEMM (T1 XCD swizzle + T2 LDS swizzle + T3/T4 counted vmcnt +
// T5 setprio). Fallback to the verified 128x128 m97-structure kernel if the
// 128 KiB dynamic-LDS launch is rejected.

typedef __attribute__((ext_vector_type(8))) __bf16 bf16x8;
typedef __attribute__((ext_vector_type(4))) float f32x4;
typedef __attribute__((ext_vector_type(8))) unsigned short u16x8;

#define BARRIER()   asm volatile("s_barrier" ::: "memory")
#define WAITLGKM0() asm volatile("s_waitcnt lgkmcnt(0)" ::: "memory")
#define WAITVM(n)   asm volatile("s_waitcnt vmcnt(" #n ")" ::: "memory")
#define SCHED0()    __builtin_amdgcn_sched_barrier(0)

__device__ __forceinline__ unsigned short f2bf(float f) {
  unsigned int u = __builtin_bit_cast(unsigned int, f);
  u += 0x7FFFu + ((u >> 16) & 1u);   // round-to-nearest-even
  return (unsigned short)(u >> 16);
}

// ---- prepass 1/3: f32 -> bf16 bulk convert (vectorized x8) ----
__global__ __launch_bounds__(256) void cvt_f32_bf16(
    const float* __restrict__ s, unsigned short* __restrict__ d, long n8) {
  long i = (long)blockIdx.x * blockDim.x + threadIdx.x;
  const long stride = (long)gridDim.x * blockDim.x;
  for (; i < n8; i += stride) {
    const float4* sp = (const float4*)(s + i * 8);
    float4 a = sp[0];
    float4 b = sp[1];
    u16x8 o;
    o[0] = f2bf(a.x); o[1] = f2bf(a.y); o[2] = f2bf(a.z); o[3] = f2bf(a.w);
    o[4] = f2bf(b.x); o[5] = f2bf(b.y); o[6] = f2bf(b.z); o[7] = f2bf(b.w);
    *(u16x8*)(d + i * 8) = o;
  }
}

// ---- prepass 2/3: scatter sparse values into bf16 W ----
__global__ __launch_bounds__(256) void sparse_scatter(
    const float* __restrict__ dense, const float* __restrict__ vals,
    const int* __restrict__ rows, const int* __restrict__ cols,
    unsigned short* __restrict__ Wb, int nnz, int K) {
  int i = blockIdx.x * blockDim.x + threadIdx.x;
  if (i < nnz) {
    size_t off = (size_t)rows[i] * (size_t)K + (size_t)cols[i];
    Wb[off] = f2bf(dense[off] + vals[i]);
  }
}

// =====================================================================
// Deep-pipelined 256x256 GEMM. 512 threads = 8 waves (2Mx4N), each wave
// owns 128x64 out = acc[8][4] of 16x16x32 frags. BK=32, LDS ring of 4
// K-tiles (A 16K + B 16K each = 128 KiB). Stage distance 3, vmcnt(8).
// LDS swizzle: 16B-quad q at row r holds global quad q ^ ((r>>1)&3)
// (conflict-free ds_read_b128; inverse applied on global src address).
// =====================================================================
__global__ __launch_bounds__(512, 2) void gemm256(
    const unsigned short* __restrict__ A,   // [Tm][K] bf16
    const unsigned short* __restrict__ B,   // [Mn][K] bf16
    const float* __restrict__ bias,
    float* __restrict__ C,
    int Tm, int Mn, int K) {
  extern __shared__ __align__(16) char smem[];   // 4 rings * 32768 B

  const int tid  = threadIdx.x;
  const int lane = tid & 63;
  const int wid  = tid >> 6;
  const int wm = (wid >> 2) * 128;   // wave row offset in tile
  const int wn = (wid & 3) * 64;     // wave col offset in tile

  // T1: XCD-aware bijective swizzle (nwg = 512, % 8 == 0)
  const int nwg = gridDim.x;
  int bid = blockIdx.x;
  if ((nwg & 7) == 0) bid = (bid & 7) * (nwg >> 3) + (bid >> 3);
  const int ntn = Mn >> 8;
  const int bm0 = (bid / ntn) << 8;
  const int bn0 = (bid % ntn) << 8;

  const int NT = K >> 5;             // K-tiles of 32

  // ---- staging config: thread t loads 16 B landing at LDS byte t*16
  // (linear, gload_lds requirement). Source quad pre-swizzled (rule #21).
  const int srow  = tid >> 2;                        // 0..127 (h adds 128)
  const int squad = (tid & 3) ^ ((tid >> 3) & 3);    // inverse swizzle
  const unsigned short* Asrc = A + (size_t)(bm0 + srow) * K + squad * 8;
  const unsigned short* Bsrc = B + (size_t)(bn0 + srow) * K + squad * 8;
  const size_t rstep = (size_t)128 * K;              // +128 rows (h=1)
  const int ldst = tid * 16;                         // LDS byte dest

#define STAGE(SRC, RING_OFF, KOFF) do {                                          \
    __builtin_amdgcn_global_load_lds(                                            \
        (const __attribute__((address_space(1))) void*)((SRC) + (KOFF)),         \
        (__attribute__((address_space(3))) void*)(smem + (RING_OFF) + ldst),     \
        16, 0, 0);                                                               \
    __builtin_amdgcn_global_load_lds(                                            \
        (const __attribute__((address_space(1))) void*)((SRC) + rstep + (KOFF)), \
        (__attribute__((address_space(3))) void*)(smem + (RING_OFF) + 8192 + ldst), \
        16, 0, 0);                                                               \
  } while (0)

  // ---- read-side offsets (swizzled): frag row = wm + m*16 + fr,
  // byte = row*64 + ((cq ^ ((row>>1)&3))*16; (row>>1)&3 == (fr>>1)&3.
  const int fr = lane & 15, cq = lane >> 4;
  const int roff = ((cq ^ ((fr >> 1) & 3)) << 4);
  const int aoff = (wm + fr) * 64 + roff;
  const int boff = (wn + fr) * 64 + roff;

  f32x4 acc[8][4] = {};

  // ---- prologue: stage tiles 0,1,2 into rings 0,1,2 (A then B each) ----
  for (int pt = 0; pt < 3; ++pt) {
    STAGE(Asrc, pt * 32768, pt * 32);
    STAGE(Bsrc, pt * 32768 + 16384, pt * 32);
  }
  WAITVM(8);          // tile 0 (4 oldest loads) landed; tiles 1,2 in flight
  BARRIER();

  // ---- main loop ----
  for (int t = 0; t < NT; ++t) {
    const int r = t & 3;
    const int so = ((t + 3) & 3) * 32768;     // stage ring (never == r)
    const char* Ar = smem + r * 32768;
    const char* Br = Ar + 16384;
    const int ks = (t + 3) * 32;
    const bool dst = (t + 3 < NT);

    bf16x8 a[4], b[4];
    // ---- phase A: read A m0-3 + B n0-3 (8 ds_read_b128), stage A(t+3) ----
#pragma unroll
    for (int m = 0; m < 4; ++m)
      a[m] = *(const bf16x8*)(Ar + aoff + m * 1024);
#pragma unroll
    for (int n = 0; n < 4; ++n)
      b[n] = *(const bf16x8*)(Br + boff + n * 1024);
    if (dst) STAGE(Asrc, so, ks);
    BARRIER();
    WAITLGKM0();
    SCHED0();
    __builtin_amdgcn_s_setprio(1);
#pragma unroll
    for (int m = 0; m < 4; ++m)
#pragma unroll
      for (int n = 0; n < 4; ++n)
        acc[m][n] = __builtin_amdgcn_mfma_f32_16x16x32_bf16(a[m], b[n], acc[m][n], 0, 0, 0);
    __builtin_amdgcn_s_setprio(0);
    BARRIER();

    // ---- phase B: read A m4-7 (4 ds_read_b128), stage B(t+3), vmcnt ----
#pragma unroll
    for (int m = 0; m < 4; ++m)
      a[m] = *(const bf16x8*)(Ar + aoff + (m + 4) * 1024);
    if (dst) STAGE(Bsrc, so + 16384, ks);
    // counted wait: tile t+1's 4 loads (oldest) landed; 8 stay in flight
    if (t + 3 < NT)      { WAITVM(8); }
    else if (t + 2 < NT) { WAITVM(4); }
    else if (t + 1 < NT) { WAITVM(0); }
    BARRIER();
    WAITLGKM0();
    SCHED0();
    __builtin_amdgcn_s_setprio(1);
#pragma unroll
    for (int m = 0; m < 4; ++m)
#pragma unroll
      for (int n = 0; n < 4; ++n)
        acc[m + 4][n] = __builtin_amdgcn_mfma_f32_16x16x32_bf16(a[m], b[n], acc[m + 4][n], 0, 0, 0);
    __builtin_amdgcn_s_setprio(0);
    BARRIER();
  }
#undef STAGE

  // ---- epilogue: C/D layout col = lane&15, row = (lane>>4)*4 + q ----
  const int c4 = cq * 4;
#pragma unroll
  for (int n = 0; n < 4; ++n) {
    const int col = bn0 + wn + n * 16 + fr;
    const float bv = bias[col];
#pragma unroll
    for (int m = 0; m < 8; ++m) {
      const size_t rowb = (size_t)(bm0 + wm + m * 16 + c4);
#pragma unroll
      for (int q = 0; q < 4; ++q)
        C[(rowb + q) * (size_t)Mn + col] = acc[m][n][q] + bv;
    }
  }
}

// ---- fallback: verified round-1 128x128 kernel (m97 structure) ----
constexpr int BM = 128, BN = 128, BK = 32;

__global__ __launch_bounds__(256, 2) void gemm_bt_bf16(
    const unsigned short* __restrict__ A, const unsigned short* __restrict__ B,
    const float* __restrict__ bias, float* __restrict__ C,
    int Tm, int Mn, int K) {
  __shared__ unsigned short As[BM * BK];
  __shared__ unsigned short Bs[BN * BK];
  const int tid = threadIdx.x;
  const int lane = tid & 63;
  const int wave = tid >> 6;
  const int nwg = gridDim.x;
  int bid = blockIdx.x;
  bid = (bid & 7) * (nwg >> 3) + (bid >> 3);
  const int ntn = Mn / BN;
  const int bm0 = (bid / ntn) * BM;
  const int bn0 = (bid % ntn) * BN;
  const int srow = tid >> 2;
  const int scol = (tid & 3) * 8;
  const unsigned short* Ag = A + (size_t)(bm0 + srow) * K + scol;
  const unsigned short* Bg = B + (size_t)(bn0 + srow) * K + scol;
  unsigned short* Al = As + tid * 8;
  unsigned short* Bl = Bs + tid * 8;
  const size_t half = (size_t)64 * K;
  const int wm = (wave >> 1) * 64;
  const int wn = (wave & 1) * 64;
  const int fr = lane & 15;
  const int fk = (lane >> 4) * 8;
  f32x4 acc[4][4] = {};
  for (int k0 = 0; k0 < K; k0 += BK) {
    __builtin_amdgcn_global_load_lds((const __attribute__((address_space(1))) void*)(Ag + k0),
        (__attribute__((address_space(3))) void*)(Al), 16, 0, 0);
    __builtin_amdgcn_global_load_lds((const __attribute__((address_space(1))) void*)(Ag + half + k0),
        (__attribute__((address_space(3))) void*)(Al + 2048), 16, 0, 0);
    __builtin_amdgcn_global_load_lds((const __attribute__((address_space(1))) void*)(Bg + k0),
        (__attribute__((address_space(3))) void*)(Bl), 16, 0, 0);
    __builtin_amdgcn_global_load_lds((const __attribute__((address_space(1))) void*)(Bg + half + k0),
        (__attribute__((address_space(3))) void*)(Bl + 2048), 16, 0, 0);
    __syncthreads();
    bf16x8 a[4], b[4];
#pragma unroll
    for (int i = 0; i < 4; ++i)
      a[i] = *reinterpret_cast<const bf16x8*>(&As[(wm + i * 16 + fr) * BK + fk]);
#pragma unroll
    for (int j = 0; j < 4; ++j)
      b[j] = *reinterpret_cast<const bf16x8*>(&Bs[(wn + j * 16 + fr) * BK + fk]);
#pragma unroll
    for (int i = 0; i < 4; ++i)
#pragma unroll
      for (int j = 0; j < 4; ++j)
        acc[i][j] = __builtin_amdgcn_mfma_f32_16x16x32_bf16(a[i], b[j], acc[i][j], 0, 0, 0);
    __syncthreads();
  }
  const int c4 = (lane >> 4) * 4;
  const int cc = lane & 15;
#pragma unroll
  for (int j = 0; j < 4; ++j) {
    const int col = bn0 + wn + j * 16 + cc;
    const float bv = bias[col];
#pragma unroll
    for (int i = 0; i < 4; ++i) {
      const int row = bm0 + wm + i * 16 + c4;
#pragma unroll
      for (int q = 0; q < 4; ++q)
        C[(size_t)(row + q) * Mn + col] = acc[i][j][q] + bv;
    }
  }
}

extern "C" void kernel_launch(void* const* d_in, const int* in_sizes, int n_in,
                              void* d_out, int out_size, void* d_ws, size_t ws_size,
                              hipStream_t stream) {
  const float* x     = (const float*)d_in[0];
  const float* dw    = (const float*)d_in[1];
  const float* bias  = (const float*)d_in[2];
  const float* sv    = (const float*)d_in[3];
  const int*   rows  = (const int*)d_in[4];
  const int*   cols  = (const int*)d_in[5];
  float* out = (float*)d_out;

  const int  Mn = in_sizes[2];                       // 4096
  const long wElems = (long)in_sizes[1];             // M*K
  const int  K  = (int)(wElems / Mn);                // 4096
  const long xElems = (long)in_sizes[0];             // T*K
  const int  Tm = (int)(xElems / K);                 // 8192
  const int  nnz = in_sizes[3];

  unsigned short* Wb = (unsigned short*)d_ws;        // [M*K] bf16
  unsigned short* Xb = Wb + wElems;                  // [T*K] bf16

  cvt_f32_bf16<<<2048, 256, 0, stream>>>(dw, Wb, wElems / 8);
  sparse_scatter<<<(nnz + 255) / 256, 256, 0, stream>>>(dw, sv, rows, cols, Wb, nnz, K);
  cvt_f32_bf16<<<2048, 256, 0, stream>>>(x, Xb, xElems / 8);

  (void)hipGetLastError();   // clear stale
  dim3 grid((Tm >> 8) * (Mn >> 8));                  // 32*16 = 512
  gemm256<<<grid, 512, 131072, stream>>>(Xb, Wb, bias, out, Tm, Mn, K);
  if (hipGetLastError() != hipSuccess) {
    // 128 KiB dynamic LDS rejected -> verified fallback
    dim3 g2((Tm / BM) * (Mn / BN));
    gemm_bt_bf16<<<g2, 256, 0, stream>>>(Xb, Wb, bias, out, Tm, Mn, K);
  }
}